// Round 1
// baseline (451.582 us; speedup 1.0000x reference)
//
#include <hip/hip_runtime.h>

#define NT    8192      // tokens (B*S)
#define DIM   1024      // d_model
#define NE    8         // experts
#define NH    512       // hidden
#define NROWS (NT*2)    // token-expert assignments (top_k=2)

typedef _Float16 f16;
typedef __attribute__((ext_vector_type(8))) _Float16 f16x8;
typedef __attribute__((ext_vector_type(4))) _Float16 f16x4;
typedef __attribute__((ext_vector_type(4))) float f32x4;

// ---------------- router: logits -> softmax -> top2 + histogram ----------------
// one token per 8-lane group; lane&7 = expert. wr staged in LDS (conflict-free:
// 8 lanes broadcast-read same address per expert column).
__global__ __launch_bounds__(256) void router_kernel(
    const float* __restrict__ x, const float* __restrict__ wr,
    int* __restrict__ eidx, float* __restrict__ gw, int* __restrict__ counts)
{
    __shared__ float lwr[DIM*NE];   // 32 KiB
    int tid = threadIdx.x;
    for (int i = tid; i < DIM*NE; i += 256) lwr[i] = wr[i];
    __syncthreads();
    int lane = tid & 63;
    int wv   = tid >> 6;
    int grp  = lane >> 3;
    int e    = lane & 7;
    int t    = blockIdx.x*32 + wv*8 + grp;
    const float* xrow = x + (size_t)t*DIM;
    float acc = 0.f;
    for (int d = 0; d < DIM; d += 4) {
        float4 xv = *(const float4*)(xrow + d);
        acc += xv.x*lwr[(d+0)*NE+e];
        acc += xv.y*lwr[(d+1)*NE+e];
        acc += xv.z*lwr[(d+2)*NE+e];
        acc += xv.w*lwr[(d+3)*NE+e];
    }
    // softmax over the 8-lane group
    float m = acc;
    m = fmaxf(m, __shfl_xor(m, 1));
    m = fmaxf(m, __shfl_xor(m, 2));
    m = fmaxf(m, __shfl_xor(m, 4));
    float p = __expf(acc - m);
    float s = p;
    s += __shfl_xor(s, 1);
    s += __shfl_xor(s, 2);
    s += __shfl_xor(s, 4);
    float prob = p / s;
    // gather all 8 probs into registers on every lane
    float pv[8];
    int base = lane & 56;
    #pragma unroll
    for (int i = 0; i < 8; i++) pv[i] = __shfl(prob, base + i);
    if (e == 0) {
        int i0 = 0; float v0 = pv[0];
        #pragma unroll
        for (int i = 1; i < 8; i++) if (pv[i] > v0) { v0 = pv[i]; i0 = i; }
        int i1 = -1; float v1 = -1.f;
        #pragma unroll
        for (int i = 0; i < 8; i++) if (i != i0 && pv[i] > v1) { v1 = pv[i]; i1 = i; }
        eidx[t*2+0] = i0; gw[t*2+0] = v0;
        eidx[t*2+1] = i1; gw[t*2+1] = v1;
        atomicAdd(&counts[i0], 1);
        atomicAdd(&counts[i1], 1);
    }
}

// ---------------- exclusive scan over 8 counts ----------------
__global__ void scan_kernel(const int* __restrict__ counts, int* __restrict__ offs,
                            int* __restrict__ cursors)
{
    if (threadIdx.x == 0) {
        int s = 0;
        for (int e = 0; e < NE; e++) { offs[e] = s; cursors[e] = s; s += counts[e]; }
        offs[NE] = s;
    }
}

// ---------------- scatter assignments into per-expert buckets ----------------
__global__ __launch_bounds__(256) void scatter_kernel(
    const int* __restrict__ eidx, const float* __restrict__ gw,
    int* __restrict__ cursors, int* __restrict__ tok_ids, float* __restrict__ row_gate)
{
    int id = blockIdx.x*256 + threadIdx.x;   // 0..NROWS-1
    int e = eidx[id];
    int pos = atomicAdd(&cursors[e], 1);
    tok_ids[pos] = id >> 1;
    row_gate[pos] = gw[id];
}

// ---------------- gather x rows (permuted) + cast fp32->fp16 ----------------
__global__ __launch_bounds__(256) void gather_cast_kernel(
    const float* __restrict__ x, const int* __restrict__ tok_ids, f16* __restrict__ xg)
{
    int gid = blockIdx.x*256 + threadIdx.x;
    int r = gid >> 8;              // DIM/4 = 256 chunks per row
    int c = (gid & 255) << 2;
    int t = tok_ids[r];
    float4 v = *(const float4*)(x + (size_t)t*DIM + c);
    f16x4 o = { (f16)v.x, (f16)v.y, (f16)v.z, (f16)v.w };
    *(f16x4*)(xg + (size_t)r*DIM + c) = o;
}

// ---------------- transpose + cast: src fp32 [E][R][C] -> dst f16 [E][C][R] ----
__global__ void transpose_cast_kernel(const float* __restrict__ src,
                                      f16* __restrict__ dst, int R, int C)
{
    __shared__ float t[32][33];
    int e = blockIdx.z;
    src += (size_t)e * R * C;
    dst += (size_t)e * R * C;
    int r0 = blockIdx.y*32, c0 = blockIdx.x*32;
    int tx = threadIdx.x, ty = threadIdx.y;
    #pragma unroll
    for (int i = ty; i < 32; i += 8)
        t[i][tx] = src[(size_t)(r0+i)*C + c0 + tx];
    __syncthreads();
    #pragma unroll
    for (int i = ty; i < 32; i += 8)
        dst[(size_t)(c0+i)*R + r0 + tx] = (f16)t[tx][i];
}

// ---------------- grouped GEMM tiles ----------------
#define BM 128
#define BN 128
#define BK 32
#define LDK 40   // padded LDS K-stride (2-way bank alias only)

// GEMM1: G = silu(Xg @ W1) * (Xg @ W3), per expert. grid (NH/BN, NE, NROWS/BM)
__global__ __launch_bounds__(256,2) void gemm1_kernel(
    const f16* __restrict__ xg, const f16* __restrict__ w1t,
    const f16* __restrict__ w3t, f16* __restrict__ gbuf,
    const int* __restrict__ offs)
{
    int e = blockIdx.y;
    int off = offs[e];
    int n_e = offs[e+1] - off;
    int mt = blockIdx.z;
    if (mt*BM >= n_e) return;
    int nt = blockIdx.x;

    __shared__ f16 sA [BM*LDK];
    __shared__ f16 sB1[BN*LDK];
    __shared__ f16 sB3[BN*LDK];

    int tid = threadIdx.x;
    int lane = tid & 63, wv = tid >> 6;
    int wrow = (wv >> 1)*64, wcol = (wv & 1)*64;
    int q = lane >> 4, lm = lane & 15;

    f32x4 acc1[4][4], acc3[4][4];
    #pragma unroll
    for (int a = 0; a < 4; a++)
        #pragma unroll
        for (int b = 0; b < 4; b++) {
            acc1[a][b] = (f32x4){0.f,0.f,0.f,0.f};
            acc3[a][b] = (f32x4){0.f,0.f,0.f,0.f};
        }

    int r0 = tid >> 2;             // staging row 0..63 (+64 on 2nd pass)
    int kk = (tid & 3) * 8;        // staging k offset
    const f16* w1p = w1t + ((size_t)e*NH + nt*BN)*DIM;
    const f16* w3p = w3t + ((size_t)e*NH + nt*BN)*DIM;

    for (int k0 = 0; k0 < DIM; k0 += BK) {
        __syncthreads();
        #pragma unroll
        for (int i = 0; i < 2; i++) {
            int r = r0 + i*64;
            int rloc = mt*BM + r; rloc = rloc < n_e ? rloc : n_e - 1;
            *(f16x8*)&sA [r*LDK + kk] = *(const f16x8*)(xg  + (size_t)(off + rloc)*DIM + k0 + kk);
            *(f16x8*)&sB1[r*LDK + kk] = *(const f16x8*)(w1p + (size_t)r*DIM + k0 + kk);
            *(f16x8*)&sB3[r*LDK + kk] = *(const f16x8*)(w3p + (size_t)r*DIM + k0 + kk);
        }
        __syncthreads();
        f16x8 aF[4], b1F[4], b3F[4];
        #pragma unroll
        for (int s = 0; s < 4; s++) {
            aF[s]  = *(const f16x8*)&sA [(wrow + s*16 + lm)*LDK + q*8];
            b1F[s] = *(const f16x8*)&sB1[(wcol + s*16 + lm)*LDK + q*8];
            b3F[s] = *(const f16x8*)&sB3[(wcol + s*16 + lm)*LDK + q*8];
        }
        #pragma unroll
        for (int sr = 0; sr < 4; sr++)
            #pragma unroll
            for (int sc = 0; sc < 4; sc++) {
                acc1[sr][sc] = __builtin_amdgcn_mfma_f32_16x16x32_f16(aF[sr], b1F[sc], acc1[sr][sc], 0, 0, 0);
                acc3[sr][sc] = __builtin_amdgcn_mfma_f32_16x16x32_f16(aF[sr], b3F[sc], acc3[sr][sc], 0, 0, 0);
            }
    }
    // epilogue: silu(h1)*h3 -> f16 gbuf.  C/D: col=lane&15, row=(lane>>4)*4+reg
    #pragma unroll
    for (int sr = 0; sr < 4; sr++) {
        #pragma unroll
        for (int reg = 0; reg < 4; reg++) {
            int row = mt*BM + wrow + sr*16 + q*4 + reg;
            if (row < n_e) {
                #pragma unroll
                for (int sc = 0; sc < 4; sc++) {
                    int col = nt*BN + wcol + sc*16 + lm;
                    float g1 = acc1[sr][sc][reg];
                    float g3 = acc3[sr][sc][reg];
                    float gv = g1 / (1.f + __expf(-g1)) * g3;
                    gbuf[(size_t)(off + row)*NH + col] = (f16)gv;
                }
            }
        }
    }
}

// GEMM2: out[tok] += gate * (G @ W2). grid (DIM/BN, NE, NROWS/BM)
__global__ __launch_bounds__(256,2) void gemm2_kernel(
    const f16* __restrict__ gbuf, const f16* __restrict__ w2t,
    const int* __restrict__ offs, const int* __restrict__ tok_ids,
    const float* __restrict__ row_gate, float* __restrict__ out)
{
    int e = blockIdx.y;
    int off = offs[e];
    int n_e = offs[e+1] - off;
    int mt = blockIdx.z;
    if (mt*BM >= n_e) return;
    int nt = blockIdx.x;

    __shared__ f16 sA[BM*LDK];
    __shared__ f16 sB[BN*LDK];

    int tid = threadIdx.x;
    int lane = tid & 63, wv = tid >> 6;
    int wrow = (wv >> 1)*64, wcol = (wv & 1)*64;
    int q = lane >> 4, lm = lane & 15;

    f32x4 acc[4][4];
    #pragma unroll
    for (int a = 0; a < 4; a++)
        #pragma unroll
        for (int b = 0; b < 4; b++) acc[a][b] = (f32x4){0.f,0.f,0.f,0.f};

    int r0 = tid >> 2;
    int kk = (tid & 3) * 8;
    const f16* w2p = w2t + ((size_t)e*DIM + nt*BN)*NH;

    for (int k0 = 0; k0 < NH; k0 += BK) {
        __syncthreads();
        #pragma unroll
        for (int i = 0; i < 2; i++) {
            int r = r0 + i*64;
            int rloc = mt*BM + r; rloc = rloc < n_e ? rloc : n_e - 1;
            *(f16x8*)&sA[r*LDK + kk] = *(const f16x8*)(gbuf + (size_t)(off + rloc)*NH + k0 + kk);
            *(f16x8*)&sB[r*LDK + kk] = *(const f16x8*)(w2p  + (size_t)r*NH + k0 + kk);
        }
        __syncthreads();
        f16x8 aF[4], bF[4];
        #pragma unroll
        for (int s = 0; s < 4; s++) {
            aF[s] = *(const f16x8*)&sA[(wrow + s*16 + lm)*LDK + q*8];
            bF[s] = *(const f16x8*)&sB[(wcol + s*16 + lm)*LDK + q*8];
        }
        #pragma unroll
        for (int sr = 0; sr < 4; sr++)
            #pragma unroll
            for (int sc = 0; sc < 4; sc++)
                acc[sr][sc] = __builtin_amdgcn_mfma_f32_16x16x32_f16(aF[sr], bF[sc], acc[sr][sc], 0, 0, 0);
    }
    #pragma unroll
    for (int sr = 0; sr < 4; sr++) {
        #pragma unroll
        for (int reg = 0; reg < 4; reg++) {
            int row = mt*BM + wrow + sr*16 + q*4 + reg;
            if (row < n_e) {
                int pr = off + row;
                int t = tok_ids[pr];
                float w = row_gate[pr];
                float* orow = out + (size_t)t*DIM;
                #pragma unroll
                for (int sc = 0; sc < 4; sc++) {
                    int col = nt*BN + wcol + sc*16 + lm;
                    atomicAdd(orow + col, w * acc[sr][sc][reg]);
                }
            }
        }
    }
}

extern "C" void kernel_launch(void* const* d_in, const int* in_sizes, int n_in,
                              void* d_out, int out_size, void* d_ws, size_t ws_size,
                              hipStream_t stream)
{
    const float* x  = (const float*)d_in[0];
    const float* wr = (const float*)d_in[1];
    const float* w1 = (const float*)d_in[2];
    const float* w2 = (const float*)d_in[3];
    const float* w3 = (const float*)d_in[4];
    float* out = (float*)d_out;

    char* ws = (char*)d_ws;
    f16* xg      = (f16*)ws;        ws += (size_t)NROWS*DIM*sizeof(f16);   // 32 MiB
    f16* w1t     = (f16*)ws;        ws += (size_t)NE*NH*DIM*sizeof(f16);   // 8 MiB
    f16* w3t     = (f16*)ws;        ws += (size_t)NE*NH*DIM*sizeof(f16);   // 8 MiB
    f16* w2t     = (f16*)ws;        ws += (size_t)NE*DIM*NH*sizeof(f16);   // 8 MiB
    f16* gbuf    = (f16*)ws;        ws += (size_t)NROWS*NH*sizeof(f16);    // 16 MiB
    int* tok_ids = (int*)ws;        ws += (size_t)NROWS*4;
    float* row_gate = (float*)ws;   ws += (size_t)NROWS*4;
    int* eidx    = (int*)ws;        ws += (size_t)NROWS*4;
    float* gw    = (float*)ws;      ws += (size_t)NROWS*4;
    int* counts  = (int*)ws;        ws += 64;
    int* offs    = (int*)ws;        ws += 64;
    int* cursors = (int*)ws;        ws += 64;
    if (ws_size < (size_t)(ws - (char*)d_ws)) return;  // ~76 MB needed

    hipMemsetAsync(counts, 0, 64, stream);
    hipMemsetAsync(out, 0, (size_t)out_size*sizeof(float), stream);

    router_kernel<<<NT/32, 256, 0, stream>>>(x, wr, eidx, gw, counts);
    scan_kernel<<<1, 64, 0, stream>>>(counts, offs, cursors);
    scatter_kernel<<<NROWS/256, 256, 0, stream>>>(eidx, gw, cursors, tok_ids, row_gate);
    gather_cast_kernel<<<(NROWS*(DIM/4))/256, 256, 0, stream>>>(x, tok_ids, xg);
    dim3 tb(32, 8);
    transpose_cast_kernel<<<dim3(NH/32, DIM/32, NE), tb, 0, stream>>>(w1, w1t, DIM, NH);
    transpose_cast_kernel<<<dim3(NH/32, DIM/32, NE), tb, 0, stream>>>(w3, w3t, DIM, NH);
    transpose_cast_kernel<<<dim3(DIM/32, NH/32, NE), tb, 0, stream>>>(w2, w2t, NH, DIM);
    gemm1_kernel<<<dim3(NH/BN, NE, NROWS/BM), 256, 0, stream>>>(xg, w1t, w3t, gbuf, offs);
    gemm2_kernel<<<dim3(DIM/BN, NE, NROWS/BM), 256, 0, stream>>>(gbuf, w2t, offs, tok_ids, row_gate, out);
}

// Round 3
// 382.054 us; speedup vs baseline: 1.1820x; 1.1820x over previous
//
#include <hip/hip_runtime.h>

#define NT    8192      // tokens (B*S)
#define DIM   1024      // d_model
#define NE    8         // experts
#define NH    512       // hidden
#define NROWS (NT*2)    // token-expert assignments (top_k=2)

typedef _Float16 f16;
typedef __attribute__((ext_vector_type(8))) _Float16 f16x8;
typedef __attribute__((ext_vector_type(4))) _Float16 f16x4;
typedef __attribute__((ext_vector_type(4))) float f32x4;

// ---------------- router stage 1: split-K logits ----------------
// grid (NT/16, 2); block 256 = 16 tokens x 16 k-lanes. wr chunk staged
// transposed [e][k] in LDS; x reads fully coalesced float4.
#define KC 512
__global__ __launch_bounds__(256) void router_logits_kernel(
    const float* __restrict__ x, const float* __restrict__ wr,
    float* __restrict__ plogits)
{
    __shared__ float lw[NE*KC];   // 16 KiB
    int tid = threadIdx.x;
    int kc0 = blockIdx.y * KC;
    for (int i = tid; i < NE*KC; i += 256) {
        int k = i >> 3, e = i & 7;
        lw[e*KC + k] = wr[(size_t)kc0*NE + i];   // wr[(kc0+k)*8+e] contiguous
    }
    __syncthreads();
    int tok = blockIdx.x*16 + (tid >> 4);
    int kl  = tid & 15;
    float acc[NE];
    #pragma unroll
    for (int e = 0; e < NE; e++) acc[e] = 0.f;
    const float* xrow = x + (size_t)tok*DIM + kc0;
    #pragma unroll
    for (int i = 0; i < KC/64; i++) {
        int kb = i*64 + kl*4;
        float4 xv = *(const float4*)(xrow + kb);
        #pragma unroll
        for (int e = 0; e < NE; e++) {
            float4 wv = *(const float4*)&lw[e*KC + kb];
            acc[e] += xv.x*wv.x + xv.y*wv.y + xv.z*wv.z + xv.w*wv.w;
        }
    }
    #pragma unroll
    for (int e = 0; e < NE; e++) {
        float v = acc[e];
        v += __shfl_xor(v, 1); v += __shfl_xor(v, 2);
        v += __shfl_xor(v, 4); v += __shfl_xor(v, 8);
        acc[e] = v;
    }
    if (kl == 0) {
        float* pp = plogits + ((size_t)blockIdx.y*NT + tok)*NE;
        float4 o0 = {acc[0], acc[1], acc[2], acc[3]};
        float4 o1 = {acc[4], acc[5], acc[6], acc[7]};
        *(float4*)pp = o0;
        *(float4*)(pp + 4) = o1;
    }
}

// ---------------- router stage 2: softmax + top2 + histogram ----------------
__global__ __launch_bounds__(256) void router_top2_kernel(
    const float* __restrict__ plogits, int* __restrict__ eidx,
    float* __restrict__ gw, int* __restrict__ counts)
{
    __shared__ int hist[NE];
    if (threadIdx.x < NE) hist[threadIdx.x] = 0;
    __syncthreads();
    int t = blockIdx.x*256 + threadIdx.x;
    const float* p0 = plogits + (size_t)t*NE;
    const float* p1 = plogits + (size_t)NT*NE + (size_t)t*NE;
    float4 a0 = *(const float4*)p0, a1 = *(const float4*)(p0+4);
    float4 b0 = *(const float4*)p1, b1 = *(const float4*)(p1+4);
    float l[NE] = { a0.x+b0.x, a0.y+b0.y, a0.z+b0.z, a0.w+b0.w,
                    a1.x+b1.x, a1.y+b1.y, a1.z+b1.z, a1.w+b1.w };
    float m = l[0];
    #pragma unroll
    for (int e = 1; e < NE; e++) m = fmaxf(m, l[e]);
    float s = 0.f;
    #pragma unroll
    for (int e = 0; e < NE; e++) { l[e] = __expf(l[e] - m); s += l[e]; }
    float inv = 1.f / s;
    int i0 = 0; float v0 = l[0];
    #pragma unroll
    for (int e = 1; e < NE; e++) if (l[e] > v0) { v0 = l[e]; i0 = e; }
    int i1 = -1; float v1 = -1.f;
    #pragma unroll
    for (int e = 0; e < NE; e++) if (e != i0 && l[e] > v1) { v1 = l[e]; i1 = e; }
    eidx[t*2+0] = i0; gw[t*2+0] = v0*inv;
    eidx[t*2+1] = i1; gw[t*2+1] = v1*inv;
    atomicAdd(&hist[i0], 1);
    atomicAdd(&hist[i1], 1);
    __syncthreads();
    if (threadIdx.x < NE) atomicAdd(&counts[threadIdx.x], hist[threadIdx.x]);
}

// ---------------- exclusive scan over 8 counts ----------------
__global__ void scan_kernel(const int* __restrict__ counts, int* __restrict__ offs,
                            int* __restrict__ cursors)
{
    if (threadIdx.x == 0) {
        int s = 0;
        for (int e = 0; e < NE; e++) { offs[e] = s; cursors[e] = s; s += counts[e]; }
        offs[NE] = s;
    }
}

// ---------------- scatter assignments into per-expert buckets ----------------
__global__ __launch_bounds__(256) void scatter_kernel(
    const int* __restrict__ eidx, const float* __restrict__ gw,
    int* __restrict__ cursors, int* __restrict__ tok_ids, float* __restrict__ row_gate)
{
    int id = blockIdx.x*256 + threadIdx.x;   // 0..NROWS-1
    int e = eidx[id];
    int pos = atomicAdd(&cursors[e], 1);
    tok_ids[pos] = id >> 1;
    row_gate[pos] = gw[id];
}

// ---------------- gather x rows (permuted) + cast fp32->fp16 ----------------
__global__ __launch_bounds__(256) void gather_cast_kernel(
    const float* __restrict__ x, const int* __restrict__ tok_ids, f16* __restrict__ xg)
{
    int gid = blockIdx.x*256 + threadIdx.x;
    int r = gid >> 8;              // DIM/4 = 256 chunks per row
    int c = (gid & 255) << 2;
    int t = tok_ids[r];
    float4 v = *(const float4*)(x + (size_t)t*DIM + c);
    f16x4 o = { (f16)v.x, (f16)v.y, (f16)v.z, (f16)v.w };
    *(f16x4*)(xg + (size_t)r*DIM + c) = o;
}

// ---------------- transpose + cast: src fp32 [E][R][C] -> dst f16 [E][C][R] ----
__global__ void transpose_cast_kernel(const float* __restrict__ src,
                                      f16* __restrict__ dst, int R, int C)
{
    __shared__ float t[32][33];
    int e = blockIdx.z;
    src += (size_t)e * R * C;
    dst += (size_t)e * R * C;
    int r0 = blockIdx.y*32, c0 = blockIdx.x*32;
    int tx = threadIdx.x, ty = threadIdx.y;
    #pragma unroll
    for (int i = ty; i < 32; i += 8)
        t[i][tx] = src[(size_t)(r0+i)*C + c0 + tx];
    __syncthreads();
    #pragma unroll
    for (int i = ty; i < 32; i += 8)
        dst[(size_t)(c0+i)*R + r0 + tx] = (f16)t[tx][i];
}

// ---------------- grouped GEMM tiles ----------------
#define BM 128
#define BN 128
#define BK 32
#define LDK 40   // padded LDS K-stride

// GEMM1: G = silu(Xg @ W1) * (Xg @ W3), per expert. grid (NH/BN, NE, NROWS/BM)
__global__ __launch_bounds__(256,2) void gemm1_kernel(
    const f16* __restrict__ xg, const f16* __restrict__ w1t,
    const f16* __restrict__ w3t, f16* __restrict__ gbuf,
    const int* __restrict__ offs)
{
    int e = blockIdx.y;
    int off = offs[e];
    int n_e = offs[e+1] - off;
    int mt = blockIdx.z;
    if (mt*BM >= n_e) return;
    int nt = blockIdx.x;

    __shared__ f16 sA [BM*LDK];
    __shared__ f16 sB1[BN*LDK];
    __shared__ f16 sB3[BN*LDK];

    int tid = threadIdx.x;
    int lane = tid & 63, wv = tid >> 6;
    int wrow = (wv >> 1)*64, wcol = (wv & 1)*64;
    int q = lane >> 4, lm = lane & 15;

    f32x4 acc1[4][4], acc3[4][4];
    #pragma unroll
    for (int a = 0; a < 4; a++)
        #pragma unroll
        for (int b = 0; b < 4; b++) {
            acc1[a][b] = (f32x4){0.f,0.f,0.f,0.f};
            acc3[a][b] = (f32x4){0.f,0.f,0.f,0.f};
        }

    int r0 = tid >> 2;             // staging row 0..63 (+64 on 2nd pass)
    int kk = (tid & 3) * 8;        // staging k offset
    const f16* w1p = w1t + ((size_t)e*NH + nt*BN)*DIM;
    const f16* w3p = w3t + ((size_t)e*NH + nt*BN)*DIM;

    for (int k0 = 0; k0 < DIM; k0 += BK) {
        __syncthreads();
        #pragma unroll
        for (int i = 0; i < 2; i++) {
            int r = r0 + i*64;
            int rloc = mt*BM + r; rloc = rloc < n_e ? rloc : n_e - 1;
            *(f16x8*)&sA [r*LDK + kk] = *(const f16x8*)(xg  + (size_t)(off + rloc)*DIM + k0 + kk);
            *(f16x8*)&sB1[r*LDK + kk] = *(const f16x8*)(w1p + (size_t)r*DIM + k0 + kk);
            *(f16x8*)&sB3[r*LDK + kk] = *(const f16x8*)(w3p + (size_t)r*DIM + k0 + kk);
        }
        __syncthreads();
        f16x8 aF[4], b1F[4], b3F[4];
        #pragma unroll
        for (int s = 0; s < 4; s++) {
            aF[s]  = *(const f16x8*)&sA [(wrow + s*16 + lm)*LDK + q*8];
            b1F[s] = *(const f16x8*)&sB1[(wcol + s*16 + lm)*LDK + q*8];
            b3F[s] = *(const f16x8*)&sB3[(wcol + s*16 + lm)*LDK + q*8];
        }
        #pragma unroll
        for (int sr = 0; sr < 4; sr++)
            #pragma unroll
            for (int sc = 0; sc < 4; sc++) {
                acc1[sr][sc] = __builtin_amdgcn_mfma_f32_16x16x32_f16(aF[sr], b1F[sc], acc1[sr][sc], 0, 0, 0);
                acc3[sr][sc] = __builtin_amdgcn_mfma_f32_16x16x32_f16(aF[sr], b3F[sc], acc3[sr][sc], 0, 0, 0);
            }
    }
    // epilogue: silu(h1)*h3 -> f16 gbuf.  C/D: col=lane&15, row=(lane>>4)*4+reg
    #pragma unroll
    for (int sr = 0; sr < 4; sr++) {
        #pragma unroll
        for (int reg = 0; reg < 4; reg++) {
            int row = mt*BM + wrow + sr*16 + q*4 + reg;
            if (row < n_e) {
                #pragma unroll
                for (int sc = 0; sc < 4; sc++) {
                    int col = nt*BN + wcol + sc*16 + lm;
                    float g1 = acc1[sr][sc][reg];
                    float g3 = acc3[sr][sc][reg];
                    float gv = g1 / (1.f + __expf(-g1)) * g3;
                    gbuf[(size_t)(off + row)*NH + col] = (f16)gv;
                }
            }
        }
    }
}

// GEMM2: out[tok] += gate * (G @ W2). grid (DIM/BN, NE, NROWS/BM)
__global__ __launch_bounds__(256,2) void gemm2_kernel(
    const f16* __restrict__ gbuf, const f16* __restrict__ w2t,
    const int* __restrict__ offs, const int* __restrict__ tok_ids,
    const float* __restrict__ row_gate, float* __restrict__ out)
{
    int e = blockIdx.y;
    int off = offs[e];
    int n_e = offs[e+1] - off;
    int mt = blockIdx.z;
    if (mt*BM >= n_e) return;
    int nt = blockIdx.x;

    __shared__ f16 sA[BM*LDK];
    __shared__ f16 sB[BN*LDK];

    int tid = threadIdx.x;
    int lane = tid & 63, wv = tid >> 6;
    int wrow = (wv >> 1)*64, wcol = (wv & 1)*64;
    int q = lane >> 4, lm = lane & 15;

    f32x4 acc[4][4];
    #pragma unroll
    for (int a = 0; a < 4; a++)
        #pragma unroll
        for (int b = 0; b < 4; b++) acc[a][b] = (f32x4){0.f,0.f,0.f,0.f};

    int r0 = tid >> 2;
    int kk = (tid & 3) * 8;
    const f16* w2p = w2t + ((size_t)e*DIM + nt*BN)*NH;

    for (int k0 = 0; k0 < NH; k0 += BK) {
        __syncthreads();
        #pragma unroll
        for (int i = 0; i < 2; i++) {
            int r = r0 + i*64;
            int rloc = mt*BM + r; rloc = rloc < n_e ? rloc : n_e - 1;
            *(f16x8*)&sA[r*LDK + kk] = *(const f16x8*)(gbuf + (size_t)(off + rloc)*NH + k0 + kk);
            *(f16x8*)&sB[r*LDK + kk] = *(const f16x8*)(w2p  + (size_t)r*NH + k0 + kk);
        }
        __syncthreads();
        f16x8 aF[4], bF[4];
        #pragma unroll
        for (int s = 0; s < 4; s++) {
            aF[s] = *(const f16x8*)&sA[(wrow + s*16 + lm)*LDK + q*8];
            bF[s] = *(const f16x8*)&sB[(wcol + s*16 + lm)*LDK + q*8];
        }
        #pragma unroll
        for (int sr = 0; sr < 4; sr++)
            #pragma unroll
            for (int sc = 0; sc < 4; sc++)
                acc[sr][sc] = __builtin_amdgcn_mfma_f32_16x16x32_f16(aF[sr], bF[sc], acc[sr][sc], 0, 0, 0);
    }
    #pragma unroll
    for (int sr = 0; sr < 4; sr++) {
        #pragma unroll
        for (int reg = 0; reg < 4; reg++) {
            int row = mt*BM + wrow + sr*16 + q*4 + reg;
            if (row < n_e) {
                int pr = off + row;
                int t = tok_ids[pr];
                float w = row_gate[pr];
                float* orow = out + (size_t)t*DIM;
                #pragma unroll
                for (int sc = 0; sc < 4; sc++) {
                    int col = nt*BN + wcol + sc*16 + lm;
                    atomicAdd(orow + col, w * acc[sr][sc][reg]);
                }
            }
        }
    }
}

extern "C" void kernel_launch(void* const* d_in, const int* in_sizes, int n_in,
                              void* d_out, int out_size, void* d_ws, size_t ws_size,
                              hipStream_t stream)
{
    const float* x  = (const float*)d_in[0];
    const float* wr = (const float*)d_in[1];
    const float* w1 = (const float*)d_in[2];
    const float* w2 = (const float*)d_in[3];
    const float* w3 = (const float*)d_in[4];
    float* out = (float*)d_out;

    char* ws = (char*)d_ws;
    f16* xg      = (f16*)ws;        ws += (size_t)NROWS*DIM*sizeof(f16);   // 32 MiB
    f16* w1t     = (f16*)ws;        ws += (size_t)NE*NH*DIM*sizeof(f16);   // 8 MiB
    f16* w3t     = (f16*)ws;        ws += (size_t)NE*NH*DIM*sizeof(f16);   // 8 MiB
    f16* w2t     = (f16*)ws;        ws += (size_t)NE*DIM*NH*sizeof(f16);   // 8 MiB
    f16* gbuf    = (f16*)ws;        ws += (size_t)NROWS*NH*sizeof(f16);    // 16 MiB
    float* plogits = (float*)ws;    ws += (size_t)2*NT*NE*4;               // 512 KiB
    int* tok_ids = (int*)ws;        ws += (size_t)NROWS*4;
    float* row_gate = (float*)ws;   ws += (size_t)NROWS*4;
    int* eidx    = (int*)ws;        ws += (size_t)NROWS*4;
    float* gw    = (float*)ws;      ws += (size_t)NROWS*4;
    int* counts  = (int*)ws;        ws += 64;
    int* offs    = (int*)ws;        ws += 64;
    int* cursors = (int*)ws;        ws += 64;
    if (ws_size < (size_t)(ws - (char*)d_ws)) return;  // ~72.9 MB needed

    hipMemsetAsync(counts, 0, 64, stream);
    hipMemsetAsync(out, 0, (size_t)out_size*sizeof(float), stream);

    router_logits_kernel<<<dim3(NT/16, 2), 256, 0, stream>>>(x, wr, plogits);
    router_top2_kernel<<<NT/256, 256, 0, stream>>>(plogits, eidx, gw, counts);
    scan_kernel<<<1, 64, 0, stream>>>(counts, offs, cursors);
    scatter_kernel<<<NROWS/256, 256, 0, stream>>>(eidx, gw, cursors, tok_ids, row_gate);
    gather_cast_kernel<<<(NROWS*(DIM/4))/256, 256, 0, stream>>>(x, tok_ids, xg);
    dim3 tb(32, 8);
    transpose_cast_kernel<<<dim3(NH/32, DIM/32, NE), tb, 0, stream>>>(w1, w1t, DIM, NH);
    transpose_cast_kernel<<<dim3(NH/32, DIM/32, NE), tb, 0, stream>>>(w3, w3t, DIM, NH);
    transpose_cast_kernel<<<dim3(DIM/32, NH/32, NE), tb, 0, stream>>>(w2, w2t, NH, DIM);
    gemm1_kernel<<<dim3(NH/BN, NE, NROWS/BM), 256, 0, stream>>>(xg, w1t, w3t, gbuf, offs);
    gemm2_kernel<<<dim3(DIM/BN, NE, NROWS/BM), 256, 0, stream>>>(gbuf, w2t, offs, tok_ids, row_gate, out);
}

// Round 4
// 335.858 us; speedup vs baseline: 1.3446x; 1.1375x over previous
//
#include <hip/hip_runtime.h>

#define NT    8192      // tokens (B*S)
#define DIM   1024      // d_model
#define NE    8         // experts
#define NH    512       // hidden
#define NROWS (NT*2)    // token-expert assignments (top_k=2)

typedef _Float16 f16;
typedef __attribute__((ext_vector_type(8))) _Float16 f16x8;
typedef __attribute__((ext_vector_type(4))) _Float16 f16x4;
typedef __attribute__((ext_vector_type(2))) _Float16 f16x2;
typedef __attribute__((ext_vector_type(4))) float f32x4;

// ---------------- router stage 1: split-K logits ----------------
#define KC 512
__global__ __launch_bounds__(256) void router_logits_kernel(
    const float* __restrict__ x, const float* __restrict__ wr,
    float* __restrict__ plogits)
{
    __shared__ float lw[NE*KC];   // 16 KiB
    int tid = threadIdx.x;
    int kc0 = blockIdx.y * KC;
    for (int i = tid; i < NE*KC; i += 256) {
        int k = i >> 3, e = i & 7;
        lw[e*KC + k] = wr[(size_t)kc0*NE + i];   // wr[(kc0+k)*8+e] contiguous
    }
    __syncthreads();
    int tok = blockIdx.x*16 + (tid >> 4);
    int kl  = tid & 15;
    float acc[NE];
    #pragma unroll
    for (int e = 0; e < NE; e++) acc[e] = 0.f;
    const float* xrow = x + (size_t)tok*DIM + kc0;
    #pragma unroll
    for (int i = 0; i < KC/64; i++) {
        int kb = i*64 + kl*4;
        float4 xv = *(const float4*)(xrow + kb);
        #pragma unroll
        for (int e = 0; e < NE; e++) {
            float4 wv = *(const float4*)&lw[e*KC + kb];
            acc[e] += xv.x*wv.x + xv.y*wv.y + xv.z*wv.z + xv.w*wv.w;
        }
    }
    #pragma unroll
    for (int e = 0; e < NE; e++) {
        float v = acc[e];
        v += __shfl_xor(v, 1); v += __shfl_xor(v, 2);
        v += __shfl_xor(v, 4); v += __shfl_xor(v, 8);
        acc[e] = v;
    }
    if (kl == 0) {
        float* pp = plogits + ((size_t)blockIdx.y*NT + tok)*NE;
        float4 o0 = {acc[0], acc[1], acc[2], acc[3]};
        float4 o1 = {acc[4], acc[5], acc[6], acc[7]};
        *(float4*)pp = o0;
        *(float4*)(pp + 4) = o1;
    }
}

// ---------------- router stage 2: softmax + top2 + histogram ----------------
__global__ __launch_bounds__(256) void router_top2_kernel(
    const float* __restrict__ plogits, int* __restrict__ eidx,
    float* __restrict__ gw, int* __restrict__ counts)
{
    __shared__ int hist[NE];
    if (threadIdx.x < NE) hist[threadIdx.x] = 0;
    __syncthreads();
    int t = blockIdx.x*256 + threadIdx.x;
    const float* p0 = plogits + (size_t)t*NE;
    const float* p1 = plogits + (size_t)NT*NE + (size_t)t*NE;
    float4 a0 = *(const float4*)p0, a1 = *(const float4*)(p0+4);
    float4 b0 = *(const float4*)p1, b1 = *(const float4*)(p1+4);
    float l[NE] = { a0.x+b0.x, a0.y+b0.y, a0.z+b0.z, a0.w+b0.w,
                    a1.x+b1.x, a1.y+b1.y, a1.z+b1.z, a1.w+b1.w };
    float m = l[0];
    #pragma unroll
    for (int e = 1; e < NE; e++) m = fmaxf(m, l[e]);
    float s = 0.f;
    #pragma unroll
    for (int e = 0; e < NE; e++) { l[e] = __expf(l[e] - m); s += l[e]; }
    float inv = 1.f / s;
    int i0 = 0; float v0 = l[0];
    #pragma unroll
    for (int e = 1; e < NE; e++) if (l[e] > v0) { v0 = l[e]; i0 = e; }
    int i1 = -1; float v1 = -1.f;
    #pragma unroll
    for (int e = 0; e < NE; e++) if (e != i0 && l[e] > v1) { v1 = l[e]; i1 = e; }
    eidx[t*2+0] = i0; gw[t*2+0] = v0*inv;
    eidx[t*2+1] = i1; gw[t*2+1] = v1*inv;
    atomicAdd(&hist[i0], 1);
    atomicAdd(&hist[i1], 1);
    __syncthreads();
    if (threadIdx.x < NE) atomicAdd(&counts[threadIdx.x], hist[threadIdx.x]);
}

// ---------------- exclusive scan over 8 counts ----------------
__global__ void scan_kernel(const int* __restrict__ counts, int* __restrict__ offs,
                            int* __restrict__ cursors)
{
    if (threadIdx.x == 0) {
        int s = 0;
        for (int e = 0; e < NE; e++) { offs[e] = s; cursors[e] = s; s += counts[e]; }
        offs[NE] = s;
    }
}

// ---------------- scatter assignments into per-expert buckets ----------------
// aid[pos] = assignment id (tok*2+k) so downstream output is id-addressable.
__global__ __launch_bounds__(256) void scatter_kernel(
    const int* __restrict__ eidx, const float* __restrict__ gw,
    int* __restrict__ cursors, int* __restrict__ tok_ids,
    int* __restrict__ aid, float* __restrict__ row_gate)
{
    int id = blockIdx.x*256 + threadIdx.x;   // 0..NROWS-1
    int e = eidx[id];
    int pos = atomicAdd(&cursors[e], 1);
    tok_ids[pos] = id >> 1;
    aid[pos] = id;
    row_gate[pos] = gw[id];
}

// ---------------- fused transpose+cast of w1,w3,w2 ----------------
// tensor z/8: 0 -> w1 [D][H]->[H][D], 1 -> w3, 2 -> w2 [H][D]->[D][H]
__global__ __launch_bounds__(256) void transpose_fused_kernel(
    const float* __restrict__ w1, const float* __restrict__ w3,
    const float* __restrict__ w2, f16* __restrict__ w1t,
    f16* __restrict__ w3t, f16* __restrict__ w2t)
{
    __shared__ float t[32][33];
    int z = blockIdx.y;
    int tensor = z >> 3, e = z & 7;
    const float* src; f16* dst; int R, C;
    if (tensor == 0)      { src = w1; dst = w1t; R = DIM; C = NH; }
    else if (tensor == 1) { src = w3; dst = w3t; R = DIM; C = NH; }
    else                  { src = w2; dst = w2t; R = NH; C = DIM; }
    src += (size_t)e * DIM * NH;
    dst += (size_t)e * DIM * NH;
    int tcols = C >> 5;
    int bx = blockIdx.x % tcols, by = blockIdx.x / tcols;
    int r0 = by*32, c0 = bx*32;
    int tx = threadIdx.x, ty = threadIdx.y;
    #pragma unroll
    for (int i = ty; i < 32; i += 8)
        t[i][tx] = src[(size_t)(r0+i)*C + c0 + tx];
    __syncthreads();
    int tid = ty*32 + tx;
    int p = tid & 15;
    #pragma unroll
    for (int pass = 0; pass < 2; pass++) {
        int i = (tid >> 4) + pass*16;
        f16x2 v = { (f16)t[2*p][i], (f16)t[2*p+1][i] };
        *(f16x2*)&dst[(size_t)(c0+i)*R + r0 + 2*p] = v;
    }
}

// ---------------- grouped GEMM tiles ----------------
#define BM 128
#define BN 128
#define BK 32
#define LDK 40   // padded LDS K-stride

// GEMM1: G = silu(X @ W1) * (X @ W3). Reads x directly (fp32) via tok_ids,
// casts to f16 during LDS staging. grid (NH/BN, NE, NROWS/BM)
__global__ __launch_bounds__(256,2) void gemm1_kernel(
    const float* __restrict__ x, const int* __restrict__ tok_ids,
    const f16* __restrict__ w1t, const f16* __restrict__ w3t,
    f16* __restrict__ gbuf, const int* __restrict__ offs)
{
    int e = blockIdx.y;
    int off = offs[e];
    int n_e = offs[e+1] - off;
    int mt = blockIdx.z;
    if (mt*BM >= n_e) return;
    int nt = blockIdx.x;

    __shared__ f16 sA [BM*LDK];
    __shared__ f16 sB1[BN*LDK];
    __shared__ f16 sB3[BN*LDK];
    __shared__ int stok[BM];

    int tid = threadIdx.x;
    if (tid < BM) {
        int rloc = mt*BM + tid; rloc = rloc < n_e ? rloc : n_e - 1;
        stok[tid] = tok_ids[off + rloc];
    }
    __syncthreads();

    int lane = tid & 63, wv = tid >> 6;
    int wrow = (wv >> 1)*64, wcol = (wv & 1)*64;
    int q = lane >> 4, lm = lane & 15;

    f32x4 acc1[4][4], acc3[4][4];
    #pragma unroll
    for (int a = 0; a < 4; a++)
        #pragma unroll
        for (int b = 0; b < 4; b++) {
            acc1[a][b] = (f32x4){0.f,0.f,0.f,0.f};
            acc3[a][b] = (f32x4){0.f,0.f,0.f,0.f};
        }

    int r0 = tid >> 2;             // staging row 0..63 (+64 on 2nd pass)
    int kk = (tid & 3) * 8;        // staging k offset (elements)
    const f16* w1p = w1t + ((size_t)e*NH + nt*BN)*DIM;
    const f16* w3p = w3t + ((size_t)e*NH + nt*BN)*DIM;

    for (int k0 = 0; k0 < DIM; k0 += BK) {
        __syncthreads();
        #pragma unroll
        for (int i = 0; i < 2; i++) {
            int r = r0 + i*64;
            const float* xp = x + (size_t)stok[r]*DIM + k0 + kk;
            float4 xa = *(const float4*)xp;
            float4 xb = *(const float4*)(xp + 4);
            f16x8 av = { (f16)xa.x, (f16)xa.y, (f16)xa.z, (f16)xa.w,
                         (f16)xb.x, (f16)xb.y, (f16)xb.z, (f16)xb.w };
            *(f16x8*)&sA [r*LDK + kk] = av;
            *(f16x8*)&sB1[r*LDK + kk] = *(const f16x8*)(w1p + (size_t)r*DIM + k0 + kk);
            *(f16x8*)&sB3[r*LDK + kk] = *(const f16x8*)(w3p + (size_t)r*DIM + k0 + kk);
        }
        __syncthreads();
        f16x8 aF[4], b1F[4], b3F[4];
        #pragma unroll
        for (int s = 0; s < 4; s++) {
            aF[s]  = *(const f16x8*)&sA [(wrow + s*16 + lm)*LDK + q*8];
            b1F[s] = *(const f16x8*)&sB1[(wcol + s*16 + lm)*LDK + q*8];
            b3F[s] = *(const f16x8*)&sB3[(wcol + s*16 + lm)*LDK + q*8];
        }
        #pragma unroll
        for (int sr = 0; sr < 4; sr++)
            #pragma unroll
            for (int sc = 0; sc < 4; sc++) {
                acc1[sr][sc] = __builtin_amdgcn_mfma_f32_16x16x32_f16(aF[sr], b1F[sc], acc1[sr][sc], 0, 0, 0);
                acc3[sr][sc] = __builtin_amdgcn_mfma_f32_16x16x32_f16(aF[sr], b3F[sc], acc3[sr][sc], 0, 0, 0);
            }
    }
    // epilogue: silu(h1)*h3 -> f16 gbuf.  C/D: col=lane&15, row=(lane>>4)*4+reg
    #pragma unroll
    for (int sr = 0; sr < 4; sr++) {
        #pragma unroll
        for (int reg = 0; reg < 4; reg++) {
            int row = mt*BM + wrow + sr*16 + q*4 + reg;
            if (row < n_e) {
                #pragma unroll
                for (int sc = 0; sc < 4; sc++) {
                    int col = nt*BN + wcol + sc*16 + lm;
                    float g1 = acc1[sr][sc][reg];
                    float g3 = acc3[sr][sc][reg];
                    float gv = g1 / (1.f + __expf(-g1)) * g3;
                    gbuf[(size_t)(off + row)*NH + col] = (f16)gv;
                }
            }
        }
    }
}

// GEMM2: ybuf[aid[row]] = gate * (G @ W2), plain f16 stores — no atomics.
// ybuf is written by THIS kernel only (single-writer rule).
// grid (DIM/BN, NE, NROWS/BM)
__global__ __launch_bounds__(256,2) void gemm2_kernel(
    const f16* __restrict__ gbuf, const f16* __restrict__ w2t,
    const int* __restrict__ offs, const int* __restrict__ aid,
    const float* __restrict__ row_gate, f16* __restrict__ ybuf)
{
    int e = blockIdx.y;
    int off = offs[e];
    int n_e = offs[e+1] - off;
    int mt = blockIdx.z;
    if (mt*BM >= n_e) return;
    int nt = blockIdx.x;

    __shared__ f16 sA[BM*LDK];
    __shared__ f16 sB[BN*LDK];
    __shared__ int said[BM];
    __shared__ float sgate[BM];

    int tid = threadIdx.x;
    if (tid < BM) {
        int rloc = mt*BM + tid;
        if (rloc < n_e) { said[tid] = aid[off + rloc]; sgate[tid] = row_gate[off + rloc]; }
        else            { said[tid] = 0; sgate[tid] = 0.f; }
    }
    __syncthreads();

    int lane = tid & 63, wv = tid >> 6;
    int wrow = (wv >> 1)*64, wcol = (wv & 1)*64;
    int q = lane >> 4, lm = lane & 15;

    f32x4 acc[4][4];
    #pragma unroll
    for (int a = 0; a < 4; a++)
        #pragma unroll
        for (int b = 0; b < 4; b++) acc[a][b] = (f32x4){0.f,0.f,0.f,0.f};

    int r0 = tid >> 2;
    int kk = (tid & 3) * 8;
    const f16* w2p = w2t + ((size_t)e*DIM + nt*BN)*NH;

    for (int k0 = 0; k0 < NH; k0 += BK) {
        __syncthreads();
        #pragma unroll
        for (int i = 0; i < 2; i++) {
            int r = r0 + i*64;
            int rloc = mt*BM + r; rloc = rloc < n_e ? rloc : n_e - 1;
            *(f16x8*)&sA[r*LDK + kk] = *(const f16x8*)(gbuf + (size_t)(off + rloc)*NH + k0 + kk);
            *(f16x8*)&sB[r*LDK + kk] = *(const f16x8*)(w2p  + (size_t)r*NH + k0 + kk);
        }
        __syncthreads();
        f16x8 aF[4], bF[4];
        #pragma unroll
        for (int s = 0; s < 4; s++) {
            aF[s] = *(const f16x8*)&sA[(wrow + s*16 + lm)*LDK + q*8];
            bF[s] = *(const f16x8*)&sB[(wcol + s*16 + lm)*LDK + q*8];
        }
        #pragma unroll
        for (int sr = 0; sr < 4; sr++)
            #pragma unroll
            for (int sc = 0; sc < 4; sc++)
                acc[sr][sc] = __builtin_amdgcn_mfma_f32_16x16x32_f16(aF[sr], bF[sc], acc[sr][sc], 0, 0, 0);
    }
    #pragma unroll
    for (int sr = 0; sr < 4; sr++) {
        #pragma unroll
        for (int reg = 0; reg < 4; reg++) {
            int lrow = wrow + sr*16 + q*4 + reg;
            if (mt*BM + lrow < n_e) {
                int id = said[lrow];
                float w = sgate[lrow];
                #pragma unroll
                for (int sc = 0; sc < 4; sc++) {
                    int col = nt*BN + wcol + sc*16 + lm;
                    ybuf[(size_t)id*DIM + col] = (f16)(w * acc[sr][sc][reg]);
                }
            }
        }
    }
}

// ---------------- combine: out[t] = ybuf[2t] + ybuf[2t+1] (no indirection) ----
__global__ __launch_bounds__(256) void combine_kernel(
    const f16* __restrict__ ybuf, float* __restrict__ out)
{
    int gid = blockIdx.x*256 + threadIdx.x;
    int t = gid >> 7;              // 128 chunks of 8 per row
    int c = (gid & 127) << 3;
    f16x8 y0 = *(const f16x8*)(ybuf + ((size_t)2*t)*DIM + c);
    f16x8 y1 = *(const f16x8*)(ybuf + ((size_t)2*t+1)*DIM + c);
    float* op = out + (size_t)t*DIM + c;
    float4 o0 = { (float)y0[0] + (float)y1[0], (float)y0[1] + (float)y1[1],
                  (float)y0[2] + (float)y1[2], (float)y0[3] + (float)y1[3] };
    float4 o1 = { (float)y0[4] + (float)y1[4], (float)y0[5] + (float)y1[5],
                  (float)y0[6] + (float)y1[6], (float)y0[7] + (float)y1[7] };
    *(float4*)op = o0;
    *(float4*)(op + 4) = o1;
}

extern "C" void kernel_launch(void* const* d_in, const int* in_sizes, int n_in,
                              void* d_out, int out_size, void* d_ws, size_t ws_size,
                              hipStream_t stream)
{
    const float* x  = (const float*)d_in[0];
    const float* wr = (const float*)d_in[1];
    const float* w1 = (const float*)d_in[2];
    const float* w2 = (const float*)d_in[3];
    const float* w3 = (const float*)d_in[4];
    float* out = (float*)d_out;

    char* ws = (char*)d_ws;
    f16* ybuf    = (f16*)ws;        ws += (size_t)NROWS*DIM*sizeof(f16);   // 32 MiB (writer: gemm2 only)
    f16* w1t     = (f16*)ws;        ws += (size_t)NE*NH*DIM*sizeof(f16);   // 8 MiB
    f16* w3t     = (f16*)ws;        ws += (size_t)NE*NH*DIM*sizeof(f16);   // 8 MiB
    f16* w2t     = (f16*)ws;        ws += (size_t)NE*DIM*NH*sizeof(f16);   // 8 MiB
    f16* gbuf    = (f16*)ws;        ws += (size_t)NROWS*NH*sizeof(f16);    // 16 MiB
    float* plogits = (float*)ws;    ws += (size_t)2*NT*NE*4;               // 512 KiB
    int* tok_ids = (int*)ws;        ws += (size_t)NROWS*4;
    int* aid     = (int*)ws;        ws += (size_t)NROWS*4;
    float* row_gate = (float*)ws;   ws += (size_t)NROWS*4;
    int* eidx    = (int*)ws;        ws += (size_t)NROWS*4;
    float* gw    = (float*)ws;      ws += (size_t)NROWS*4;
    int* counts  = (int*)ws;        ws += 64;
    int* offs    = (int*)ws;        ws += 64;
    int* cursors = (int*)ws;        ws += 64;
    if (ws_size < (size_t)(ws - (char*)d_ws)) return;  // ~73 MB needed

    hipMemsetAsync(counts, 0, 64, stream);

    router_logits_kernel<<<dim3(NT/16, 2), 256, 0, stream>>>(x, wr, plogits);
    router_top2_kernel<<<NT/256, 256, 0, stream>>>(plogits, eidx, gw, counts);
    scan_kernel<<<1, 64, 0, stream>>>(counts, offs, cursors);
    scatter_kernel<<<NROWS/256, 256, 0, stream>>>(eidx, gw, cursors, tok_ids, aid, row_gate);
    transpose_fused_kernel<<<dim3(512, 24), dim3(32, 8), 0, stream>>>(w1, w3, w2, w1t, w3t, w2t);
    gemm1_kernel<<<dim3(NH/BN, NE, NROWS/BM), 256, 0, stream>>>(x, tok_ids, w1t, w3t, gbuf, offs);
    gemm2_kernel<<<dim3(DIM/BN, NE, NROWS/BM), 256, 0, stream>>>(gbuf, w2t, offs, aid, row_gate, ybuf);
    combine_kernel<<<(NT*(DIM/8))/256, 256, 0, stream>>>(ybuf, out);
}

// Round 5
// 297.320 us; speedup vs baseline: 1.5188x; 1.1296x over previous
//
#include <hip/hip_runtime.h>

#define NT    8192      // tokens (B*S)
#define DIM   1024      // d_model
#define NE    8         // experts
#define NH    512       // hidden
#define NROWS (NT*2)    // token-expert assignments (top_k=2)

typedef _Float16 f16;
typedef __attribute__((ext_vector_type(8))) _Float16 f16x8;
typedef __attribute__((ext_vector_type(4))) _Float16 f16x4;
typedef __attribute__((ext_vector_type(2))) _Float16 f16x2;
typedef __attribute__((ext_vector_type(4))) float f32x4;

// ---------------- router stage 1: split-K logits ----------------
#define KC 512
__global__ __launch_bounds__(256) void router_logits_kernel(
    const float* __restrict__ x, const float* __restrict__ wr,
    float* __restrict__ plogits)
{
    __shared__ float lw[NE*KC];   // 16 KiB
    int tid = threadIdx.x;
    int kc0 = blockIdx.y * KC;
    for (int i = tid; i < NE*KC; i += 256) {
        int k = i >> 3, e = i & 7;
        lw[e*KC + k] = wr[(size_t)kc0*NE + i];   // wr[(kc0+k)*8+e] contiguous
    }
    __syncthreads();
    int tok = blockIdx.x*16 + (tid >> 4);
    int kl  = tid & 15;
    float acc[NE];
    #pragma unroll
    for (int e = 0; e < NE; e++) acc[e] = 0.f;
    const float* xrow = x + (size_t)tok*DIM + kc0;
    #pragma unroll
    for (int i = 0; i < KC/64; i++) {
        int kb = i*64 + kl*4;
        float4 xv = *(const float4*)(xrow + kb);
        #pragma unroll
        for (int e = 0; e < NE; e++) {
            float4 wv = *(const float4*)&lw[e*KC + kb];
            acc[e] += xv.x*wv.x + xv.y*wv.y + xv.z*wv.z + xv.w*wv.w;
        }
    }
    #pragma unroll
    for (int e = 0; e < NE; e++) {
        float v = acc[e];
        v += __shfl_xor(v, 1); v += __shfl_xor(v, 2);
        v += __shfl_xor(v, 4); v += __shfl_xor(v, 8);
        acc[e] = v;
    }
    if (kl == 0) {
        float* pp = plogits + ((size_t)blockIdx.y*NT + tok)*NE;
        float4 o0 = {acc[0], acc[1], acc[2], acc[3]};
        float4 o1 = {acc[4], acc[5], acc[6], acc[7]};
        *(float4*)pp = o0;
        *(float4*)(pp + 4) = o1;
    }
}

// ---------------- finalize: softmax+top2 + hist + scan + ranked scatter ------
// Single block, 1024 threads. All intermediate state in LDS; ballot-based
// counting (no per-element LDS atomics). Bucket order is nondeterministic
// across replays but output is aid-addressed -> bitwise deterministic.
__global__ __launch_bounds__(1024) void finalize_kernel(
    const float* __restrict__ plogits, int* __restrict__ tok_ids,
    int* __restrict__ aid, float* __restrict__ row_gate, int* __restrict__ offs)
{
    __shared__ unsigned char s_e[NROWS];   // 16 KB
    __shared__ float s_w[NROWS];           // 64 KB
    __shared__ int hist[NE], cur[NE];
    int tid = threadIdx.x;
    if (tid < NE) hist[tid] = 0;
    __syncthreads();

    // phase 1: top-2 per token + wave-ballot histogram
    #pragma unroll 1
    for (int it = 0; it < NT/1024; it++) {
        int t = it*1024 + tid;
        const float* p0 = plogits + (size_t)t*NE;
        const float* p1 = plogits + (size_t)NT*NE + (size_t)t*NE;
        float4 a0 = *(const float4*)p0, a1 = *(const float4*)(p0+4);
        float4 b0 = *(const float4*)p1, b1 = *(const float4*)(p1+4);
        float l[NE] = { a0.x+b0.x, a0.y+b0.y, a0.z+b0.z, a0.w+b0.w,
                        a1.x+b1.x, a1.y+b1.y, a1.z+b1.z, a1.w+b1.w };
        float m = l[0];
        #pragma unroll
        for (int e = 1; e < NE; e++) m = fmaxf(m, l[e]);
        float s = 0.f;
        #pragma unroll
        for (int e = 0; e < NE; e++) { l[e] = __expf(l[e] - m); s += l[e]; }
        float inv = 1.f / s;
        int i0 = 0; float v0 = l[0];
        #pragma unroll
        for (int e = 1; e < NE; e++) if (l[e] > v0) { v0 = l[e]; i0 = e; }
        int i1 = -1; float v1 = -1.f;
        #pragma unroll
        for (int e = 0; e < NE; e++) if (e != i0 && l[e] > v1) { v1 = l[e]; i1 = e; }
        s_e[t*2+0] = (unsigned char)i0; s_w[t*2+0] = v0*inv;
        s_e[t*2+1] = (unsigned char)i1; s_w[t*2+1] = v1*inv;
        #pragma unroll
        for (int ee = 0; ee < NE; ee++) {
            int c = __popcll(__ballot(i0 == ee)) + __popcll(__ballot(i1 == ee));
            if ((tid & 63) == 0 && c) atomicAdd(&hist[ee], c);
        }
    }
    __syncthreads();

    // phase 2: exclusive scan
    if (tid == 0) {
        int s = 0;
        #pragma unroll
        for (int e = 0; e < NE; e++) { offs[e] = s; cur[e] = s; s += hist[e]; }
        offs[NE] = s;
    }
    __syncthreads();

    // phase 3: ranked scatter (ballot prefix within wave, one atomic per wave/e)
    unsigned long long ltmask = (1ULL << (tid & 63)) - 1;
    #pragma unroll 1
    for (int it = 0; it < NROWS/1024; it++) {
        int id = it*1024 + tid;
        int e = s_e[id];
        int pos = 0;
        #pragma unroll
        for (int ee = 0; ee < NE; ee++) {
            unsigned long long mk = __ballot(e == ee);
            int cnt = __popcll(mk);
            int b = 0;
            if ((tid & 63) == 0 && cnt) b = atomicAdd(&cur[ee], cnt);
            b = __shfl(b, 0);
            if (e == ee) pos = b + __popcll(mk & ltmask);
        }
        tok_ids[pos] = id >> 1;
        aid[pos] = id;
        row_gate[pos] = s_w[id];
    }
}

// ---------------- fused transpose+cast of w1,w3,w2 ----------------
__global__ __launch_bounds__(256) void transpose_fused_kernel(
    const float* __restrict__ w1, const float* __restrict__ w3,
    const float* __restrict__ w2, f16* __restrict__ w1t,
    f16* __restrict__ w3t, f16* __restrict__ w2t)
{
    __shared__ float t[32][33];
    int z = blockIdx.y;
    int tensor = z >> 3, e = z & 7;
    const float* src; f16* dst; int R, C;
    if (tensor == 0)      { src = w1; dst = w1t; R = DIM; C = NH; }
    else if (tensor == 1) { src = w3; dst = w3t; R = DIM; C = NH; }
    else                  { src = w2; dst = w2t; R = NH; C = DIM; }
    src += (size_t)e * DIM * NH;
    dst += (size_t)e * DIM * NH;
    int tcols = C >> 5;
    int bx = blockIdx.x % tcols, by = blockIdx.x / tcols;
    int r0 = by*32, c0 = bx*32;
    int tx = threadIdx.x, ty = threadIdx.y;
    #pragma unroll
    for (int i = ty; i < 32; i += 8)
        t[i][tx] = src[(size_t)(r0+i)*C + c0 + tx];
    __syncthreads();
    int tid = ty*32 + tx;
    int p = tid & 15;
    #pragma unroll
    for (int pass = 0; pass < 2; pass++) {
        int i = (tid >> 4) + pass*16;
        f16x2 v = { (f16)t[2*p][i], (f16)t[2*p+1][i] };
        *(f16x2*)&dst[(size_t)(c0+i)*R + r0 + 2*p] = v;
    }
}

// ---------------- grouped GEMM tiles ----------------
#define BM 128
#define BN 128
#define BK 32
#define LDK 40   // padded LDS K-stride

// GEMM1: G = silu(X @ W1) * (X @ W3). 1D grid, XCD swizzle: e = bi&7 so each
// expert's weight slice stays resident in one XCD's L2; nt innermost so
// temporally-adjacent same-XCD blocks share the A-tile.
__global__ __launch_bounds__(256,2) void gemm1_kernel(
    const float* __restrict__ x, const int* __restrict__ tok_ids,
    const f16* __restrict__ w1t, const f16* __restrict__ w3t,
    f16* __restrict__ gbuf, const int* __restrict__ offs)
{
    int bi = blockIdx.x;
    int e  = bi & 7;
    int r_ = bi >> 3;
    int nt = r_ & 3;          // NH/BN = 4
    int mt = r_ >> 2;         // 0..127
    int off = offs[e];
    int n_e = offs[e+1] - off;
    if (mt*BM >= n_e) return;

    __shared__ f16 sA [BM*LDK];
    __shared__ f16 sB1[BN*LDK];
    __shared__ f16 sB3[BN*LDK];
    __shared__ int stok[BM];

    int tid = threadIdx.x;
    if (tid < BM) {
        int rloc = mt*BM + tid; rloc = rloc < n_e ? rloc : n_e - 1;
        stok[tid] = tok_ids[off + rloc];
    }
    __syncthreads();

    int lane = tid & 63, wv = tid >> 6;
    int wrow = (wv >> 1)*64, wcol = (wv & 1)*64;
    int q = lane >> 4, lm = lane & 15;

    f32x4 acc1[4][4], acc3[4][4];
    #pragma unroll
    for (int a = 0; a < 4; a++)
        #pragma unroll
        for (int b = 0; b < 4; b++) {
            acc1[a][b] = (f32x4){0.f,0.f,0.f,0.f};
            acc3[a][b] = (f32x4){0.f,0.f,0.f,0.f};
        }

    int r0 = tid >> 2;             // staging row 0..63 (+64 on 2nd pass)
    int kk = (tid & 3) * 8;        // staging k offset (elements)
    const f16* w1p = w1t + ((size_t)e*NH + nt*BN)*DIM;
    const f16* w3p = w3t + ((size_t)e*NH + nt*BN)*DIM;

    for (int k0 = 0; k0 < DIM; k0 += BK) {
        __syncthreads();
        #pragma unroll
        for (int i = 0; i < 2; i++) {
            int r = r0 + i*64;
            const float* xp = x + (size_t)stok[r]*DIM + k0 + kk;
            float4 xa = *(const float4*)xp;
            float4 xb = *(const float4*)(xp + 4);
            f16x8 av = { (f16)xa.x, (f16)xa.y, (f16)xa.z, (f16)xa.w,
                         (f16)xb.x, (f16)xb.y, (f16)xb.z, (f16)xb.w };
            *(f16x8*)&sA [r*LDK + kk] = av;
            *(f16x8*)&sB1[r*LDK + kk] = *(const f16x8*)(w1p + (size_t)r*DIM + k0 + kk);
            *(f16x8*)&sB3[r*LDK + kk] = *(const f16x8*)(w3p + (size_t)r*DIM + k0 + kk);
        }
        __syncthreads();
        f16x8 aF[4], b1F[4], b3F[4];
        #pragma unroll
        for (int s = 0; s < 4; s++) {
            aF[s]  = *(const f16x8*)&sA [(wrow + s*16 + lm)*LDK + q*8];
            b1F[s] = *(const f16x8*)&sB1[(wcol + s*16 + lm)*LDK + q*8];
            b3F[s] = *(const f16x8*)&sB3[(wcol + s*16 + lm)*LDK + q*8];
        }
        #pragma unroll
        for (int sr = 0; sr < 4; sr++)
            #pragma unroll
            for (int sc = 0; sc < 4; sc++) {
                acc1[sr][sc] = __builtin_amdgcn_mfma_f32_16x16x32_f16(aF[sr], b1F[sc], acc1[sr][sc], 0, 0, 0);
                acc3[sr][sc] = __builtin_amdgcn_mfma_f32_16x16x32_f16(aF[sr], b3F[sc], acc3[sr][sc], 0, 0, 0);
            }
    }
    // epilogue: silu(h1)*h3 -> f16 gbuf.  C/D: col=lane&15, row=(lane>>4)*4+reg
    #pragma unroll
    for (int sr = 0; sr < 4; sr++) {
        #pragma unroll
        for (int reg = 0; reg < 4; reg++) {
            int row = mt*BM + wrow + sr*16 + q*4 + reg;
            if (row < n_e) {
                #pragma unroll
                for (int sc = 0; sc < 4; sc++) {
                    int col = nt*BN + wcol + sc*16 + lm;
                    float g1 = acc1[sr][sc][reg];
                    float g3 = acc3[sr][sc][reg];
                    float gv = g1 / (1.f + __expf(-g1)) * g3;
                    gbuf[(size_t)(off + row)*NH + col] = (f16)gv;
                }
            }
        }
    }
}

// GEMM2: ybuf[aid[row]] = gate * (G @ W2), plain f16 stores. Same XCD swizzle.
__global__ __launch_bounds__(256,4) void gemm2_kernel(
    const f16* __restrict__ gbuf, const f16* __restrict__ w2t,
    const int* __restrict__ offs, const int* __restrict__ aid,
    const float* __restrict__ row_gate, f16* __restrict__ ybuf)
{
    int bi = blockIdx.x;
    int e  = bi & 7;
    int r_ = bi >> 3;
    int nt = r_ & 7;          // DIM/BN = 8
    int mt = r_ >> 3;         // 0..127
    int off = offs[e];
    int n_e = offs[e+1] - off;
    if (mt*BM >= n_e) return;

    __shared__ f16 sA[BM*LDK];
    __shared__ f16 sB[BN*LDK];
    __shared__ int said[BM];
    __shared__ float sgate[BM];

    int tid = threadIdx.x;
    if (tid < BM) {
        int rloc = mt*BM + tid;
        if (rloc < n_e) { said[tid] = aid[off + rloc]; sgate[tid] = row_gate[off + rloc]; }
        else            { said[tid] = 0; sgate[tid] = 0.f; }
    }
    __syncthreads();

    int lane = tid & 63, wv = tid >> 6;
    int wrow = (wv >> 1)*64, wcol = (wv & 1)*64;
    int q = lane >> 4, lm = lane & 15;

    f32x4 acc[4][4];
    #pragma unroll
    for (int a = 0; a < 4; a++)
        #pragma unroll
        for (int b = 0; b < 4; b++) acc[a][b] = (f32x4){0.f,0.f,0.f,0.f};

    int r0 = tid >> 2;
    int kk = (tid & 3) * 8;
    const f16* w2p = w2t + ((size_t)e*DIM + nt*BN)*NH;

    for (int k0 = 0; k0 < NH; k0 += BK) {
        __syncthreads();
        #pragma unroll
        for (int i = 0; i < 2; i++) {
            int r = r0 + i*64;
            int rloc = mt*BM + r; rloc = rloc < n_e ? rloc : n_e - 1;
            *(f16x8*)&sA[r*LDK + kk] = *(const f16x8*)(gbuf + (size_t)(off + rloc)*NH + k0 + kk);
            *(f16x8*)&sB[r*LDK + kk] = *(const f16x8*)(w2p  + (size_t)r*NH + k0 + kk);
        }
        __syncthreads();
        f16x8 aF[4], bF[4];
        #pragma unroll
        for (int s = 0; s < 4; s++) {
            aF[s] = *(const f16x8*)&sA[(wrow + s*16 + lm)*LDK + q*8];
            bF[s] = *(const f16x8*)&sB[(wcol + s*16 + lm)*LDK + q*8];
        }
        #pragma unroll
        for (int sr = 0; sr < 4; sr++)
            #pragma unroll
            for (int sc = 0; sc < 4; sc++)
                acc[sr][sc] = __builtin_amdgcn_mfma_f32_16x16x32_f16(aF[sr], bF[sc], acc[sr][sc], 0, 0, 0);
    }
    #pragma unroll
    for (int sr = 0; sr < 4; sr++) {
        #pragma unroll
        for (int reg = 0; reg < 4; reg++) {
            int lrow = wrow + sr*16 + q*4 + reg;
            if (mt*BM + lrow < n_e) {
                int id = said[lrow];
                float w = sgate[lrow];
                #pragma unroll
                for (int sc = 0; sc < 4; sc++) {
                    int col = nt*BN + wcol + sc*16 + lm;
                    ybuf[(size_t)id*DIM + col] = (f16)(w * acc[sr][sc][reg]);
                }
            }
        }
    }
}

// ---------------- combine: out[t] = ybuf[2t] + ybuf[2t+1] ----------------
__global__ __launch_bounds__(256) void combine_kernel(
    const f16* __restrict__ ybuf, float* __restrict__ out)
{
    int gid = blockIdx.x*256 + threadIdx.x;
    int t = gid >> 7;              // 128 chunks of 8 per row
    int c = (gid & 127) << 3;
    f16x8 y0 = *(const f16x8*)(ybuf + ((size_t)2*t)*DIM + c);
    f16x8 y1 = *(const f16x8*)(ybuf + ((size_t)2*t+1)*DIM + c);
    float* op = out + (size_t)t*DIM + c;
    float4 o0 = { (float)y0[0] + (float)y1[0], (float)y0[1] + (float)y1[1],
                  (float)y0[2] + (float)y1[2], (float)y0[3] + (float)y1[3] };
    float4 o1 = { (float)y0[4] + (float)y1[4], (float)y0[5] + (float)y1[5],
                  (float)y0[6] + (float)y1[6], (float)y0[7] + (float)y1[7] };
    *(float4*)op = o0;
    *(float4*)(op + 4) = o1;
}

extern "C" void kernel_launch(void* const* d_in, const int* in_sizes, int n_in,
                              void* d_out, int out_size, void* d_ws, size_t ws_size,
                              hipStream_t stream)
{
    const float* x  = (const float*)d_in[0];
    const float* wr = (const float*)d_in[1];
    const float* w1 = (const float*)d_in[2];
    const float* w2 = (const float*)d_in[3];
    const float* w3 = (const float*)d_in[4];
    float* out = (float*)d_out;

    char* ws = (char*)d_ws;
    f16* ybuf    = (f16*)ws;        ws += (size_t)NROWS*DIM*sizeof(f16);   // 32 MiB (writer: gemm2)
    f16* w1t     = (f16*)ws;        ws += (size_t)NE*NH*DIM*sizeof(f16);   // 8 MiB (writer: transpose)
    f16* w3t     = (f16*)ws;        ws += (size_t)NE*NH*DIM*sizeof(f16);   // 8 MiB (writer: transpose)
    f16* w2t     = (f16*)ws;        ws += (size_t)NE*DIM*NH*sizeof(f16);   // 8 MiB (writer: transpose)
    f16* gbuf    = (f16*)ws;        ws += (size_t)NROWS*NH*sizeof(f16);    // 16 MiB (writer: gemm1)
    float* plogits = (float*)ws;    ws += (size_t)2*NT*NE*4;               // 512 KiB (writer: router)
    int* tok_ids = (int*)ws;        ws += (size_t)NROWS*4;                 // (writer: finalize)
    int* aid     = (int*)ws;        ws += (size_t)NROWS*4;
    float* row_gate = (float*)ws;   ws += (size_t)NROWS*4;
    int* offs    = (int*)ws;        ws += 64;
    if (ws_size < (size_t)(ws - (char*)d_ws)) return;  // ~72.7 MB needed

    router_logits_kernel<<<dim3(NT/16, 2), 256, 0, stream>>>(x, wr, plogits);
    finalize_kernel<<<1, 1024, 0, stream>>>(plogits, tok_ids, aid, row_gate, offs);
    transpose_fused_kernel<<<dim3(512, 24), dim3(32, 8), 0, stream>>>(w1, w3, w2, w1t, w3t, w2t);
    gemm1_kernel<<<4096, 256, 0, stream>>>(x, tok_ids, w1t, w3t, gbuf, offs);
    gemm2_kernel<<<8192, 256, 0, stream>>>(gbuf, w2t, offs, aid, row_gate, ybuf);
    combine_kernel<<<(NT*(DIM/8))/256, 256, 0, stream>>>(ybuf, out);
}

// Round 6
// 291.015 us; speedup vs baseline: 1.5518x; 1.0217x over previous
//
#include <hip/hip_runtime.h>

#define NT    8192      // tokens (B*S)
#define DIM   1024      // d_model
#define NE    8         // experts
#define NH    512       // hidden
#define NROWS (NT*2)    // token-expert assignments (top_k=2)

typedef _Float16 f16;
typedef unsigned int u32;
typedef __attribute__((ext_vector_type(8))) _Float16 f16x8;
typedef __attribute__((ext_vector_type(4))) _Float16 f16x4;
typedef __attribute__((ext_vector_type(2))) _Float16 f16x2;
typedef __attribute__((ext_vector_type(4))) float f32x4;

// global -> LDS direct DMA, 16B per lane. LDS dest must be wave-uniform base
// + lane*16 (m104/m108); our chunk layout guarantees that by construction.
__device__ __forceinline__ void gl2lds16(const f16* gptr, f16* ldsptr) {
    __builtin_amdgcn_global_load_lds(
        (const __attribute__((address_space(1))) u32*)gptr,
        (__attribute__((address_space(3))) u32*)ldsptr, 16, 0, 0);
}

// XOR-swizzled fragment read from unpadded [rows][32] f16 LDS:
// 16B granule g holds global granule g ^ ((row>>1)&3)  ->  <=2-way conflicts.
#define FR(sbuf, row, q) \
    (*(const f16x8*)&sbuf[(row)*32 + (((q) ^ (((row) >> 1) & 3)) << 3)])

// ---------------- router stage 1: split-K logits ----------------
#define KC 512
__global__ __launch_bounds__(256) void router_logits_kernel(
    const float* __restrict__ x, const float* __restrict__ wr,
    float* __restrict__ plogits)
{
    __shared__ float lw[NE*KC];   // 16 KiB
    int tid = threadIdx.x;
    int kc0 = blockIdx.y * KC;
    for (int i = tid; i < NE*KC; i += 256) {
        int k = i >> 3, e = i & 7;
        lw[e*KC + k] = wr[(size_t)kc0*NE + i];   // wr[(kc0+k)*8+e] contiguous
    }
    __syncthreads();
    int tok = blockIdx.x*16 + (tid >> 4);
    int kl  = tid & 15;
    float acc[NE];
    #pragma unroll
    for (int e = 0; e < NE; e++) acc[e] = 0.f;
    const float* xrow = x + (size_t)tok*DIM + kc0;
    #pragma unroll
    for (int i = 0; i < KC/64; i++) {
        int kb = i*64 + kl*4;
        float4 xv = *(const float4*)(xrow + kb);
        #pragma unroll
        for (int e = 0; e < NE; e++) {
            float4 wv = *(const float4*)&lw[e*KC + kb];
            acc[e] += xv.x*wv.x + xv.y*wv.y + xv.z*wv.z + xv.w*wv.w;
        }
    }
    #pragma unroll
    for (int e = 0; e < NE; e++) {
        float v = acc[e];
        v += __shfl_xor(v, 1); v += __shfl_xor(v, 2);
        v += __shfl_xor(v, 4); v += __shfl_xor(v, 8);
        acc[e] = v;
    }
    if (kl == 0) {
        float* pp = plogits + ((size_t)blockIdx.y*NT + tok)*NE;
        float4 o0 = {acc[0], acc[1], acc[2], acc[3]};
        float4 o1 = {acc[4], acc[5], acc[6], acc[7]};
        *(float4*)pp = o0;
        *(float4*)(pp + 4) = o1;
    }
}

// ---------------- finalize: softmax+top2 + hist + scan + ranked scatter ------
__global__ __launch_bounds__(1024) void finalize_kernel(
    const float* __restrict__ plogits, int* __restrict__ tok_ids,
    int* __restrict__ aid, float* __restrict__ row_gate, int* __restrict__ offs)
{
    __shared__ unsigned char s_e[NROWS];   // 16 KB
    __shared__ float s_w[NROWS];           // 64 KB
    __shared__ int hist[NE], cur[NE];
    int tid = threadIdx.x;
    if (tid < NE) hist[tid] = 0;
    __syncthreads();

    #pragma unroll 1
    for (int it = 0; it < NT/1024; it++) {
        int t = it*1024 + tid;
        const float* p0 = plogits + (size_t)t*NE;
        const float* p1 = plogits + (size_t)NT*NE + (size_t)t*NE;
        float4 a0 = *(const float4*)p0, a1 = *(const float4*)(p0+4);
        float4 b0 = *(const float4*)p1, b1 = *(const float4*)(p1+4);
        float l[NE] = { a0.x+b0.x, a0.y+b0.y, a0.z+b0.z, a0.w+b0.w,
                        a1.x+b1.x, a1.y+b1.y, a1.z+b1.z, a1.w+b1.w };
        float m = l[0];
        #pragma unroll
        for (int e = 1; e < NE; e++) m = fmaxf(m, l[e]);
        float s = 0.f;
        #pragma unroll
        for (int e = 0; e < NE; e++) { l[e] = __expf(l[e] - m); s += l[e]; }
        float inv = 1.f / s;
        int i0 = 0; float v0 = l[0];
        #pragma unroll
        for (int e = 1; e < NE; e++) if (l[e] > v0) { v0 = l[e]; i0 = e; }
        int i1 = -1; float v1 = -1.f;
        #pragma unroll
        for (int e = 0; e < NE; e++) if (e != i0 && l[e] > v1) { v1 = l[e]; i1 = e; }
        s_e[t*2+0] = (unsigned char)i0; s_w[t*2+0] = v0*inv;
        s_e[t*2+1] = (unsigned char)i1; s_w[t*2+1] = v1*inv;
        #pragma unroll
        for (int ee = 0; ee < NE; ee++) {
            int c = __popcll(__ballot(i0 == ee)) + __popcll(__ballot(i1 == ee));
            if ((tid & 63) == 0 && c) atomicAdd(&hist[ee], c);
        }
    }
    __syncthreads();

    if (tid == 0) {
        int s = 0;
        #pragma unroll
        for (int e = 0; e < NE; e++) { offs[e] = s; cur[e] = s; s += hist[e]; }
        offs[NE] = s;
    }
    __syncthreads();

    unsigned long long ltmask = (1ULL << (tid & 63)) - 1;
    #pragma unroll 1
    for (int it = 0; it < NROWS/1024; it++) {
        int id = it*1024 + tid;
        int e = s_e[id];
        int pos = 0;
        #pragma unroll
        for (int ee = 0; ee < NE; ee++) {
            unsigned long long mk = __ballot(e == ee);
            int cnt = __popcll(mk);
            int b = 0;
            if ((tid & 63) == 0 && cnt) b = atomicAdd(&cur[ee], cnt);
            b = __shfl(b, 0);
            if (e == ee) pos = b + __popcll(mk & ltmask);
        }
        tok_ids[pos] = id >> 1;
        aid[pos] = id;
        row_gate[pos] = s_w[id];
    }
}

// ---------------- fused transpose+cast of w1,w3,w2 ----------------
__global__ __launch_bounds__(256) void transpose_fused_kernel(
    const float* __restrict__ w1, const float* __restrict__ w3,
    const float* __restrict__ w2, f16* __restrict__ w1t,
    f16* __restrict__ w3t, f16* __restrict__ w2t)
{
    __shared__ float t[32][33];
    int z = blockIdx.y;
    int tensor = z >> 3, e = z & 7;
    const float* src; f16* dst; int R, C;
    if (tensor == 0)      { src = w1; dst = w1t; R = DIM; C = NH; }
    else if (tensor == 1) { src = w3; dst = w3t; R = DIM; C = NH; }
    else                  { src = w2; dst = w2t; R = NH; C = DIM; }
    src += (size_t)e * DIM * NH;
    dst += (size_t)e * DIM * NH;
    int tcols = C >> 5;
    int bx = blockIdx.x % tcols, by = blockIdx.x / tcols;
    int r0 = by*32, c0 = bx*32;
    int tx = threadIdx.x, ty = threadIdx.y;
    #pragma unroll
    for (int i = ty; i < 32; i += 8)
        t[i][tx] = src[(size_t)(r0+i)*C + c0 + tx];
    __syncthreads();
    int tid = ty*32 + tx;
    int p = tid & 15;
    #pragma unroll
    for (int pass = 0; pass < 2; pass++) {
        int i = (tid >> 4) + pass*16;
        f16x2 v = { (f16)t[2*p][i], (f16)t[2*p+1][i] };
        *(f16x2*)&dst[(size_t)(c0+i)*R + r0 + 2*p] = v;
    }
}

// ---------------- grouped GEMM tiles ----------------
#define BM 128
#define BN 128
#define BK 32

// GEMM1: G = silu(X @ W1) * (X @ W3). XCD swizzle (e = bi&7). B1/B3 staged
// via global_load_lds DMA; A (fp32 x) via VGPR cvt + swizzled ds_write_b128.
__global__ __launch_bounds__(256,2) void gemm1_kernel(
    const float* __restrict__ x, const int* __restrict__ tok_ids,
    const f16* __restrict__ w1t, const f16* __restrict__ w3t,
    f16* __restrict__ gbuf, const int* __restrict__ offs)
{
    int bi = blockIdx.x;
    int e  = bi & 7;
    int r_ = bi >> 3;
    int nt = r_ & 3;          // NH/BN = 4
    int mt = r_ >> 2;
    int off = offs[e];
    int n_e = offs[e+1] - off;
    if (mt*BM >= n_e) return;

    __shared__ f16 sA [BM*32];   // 8 KB, unpadded, XOR-swizzled granules
    __shared__ f16 sB1[BN*32];
    __shared__ f16 sB3[BN*32];
    __shared__ int stok[BM];

    int tid = threadIdx.x;
    if (tid < BM) {
        int rloc = mt*BM + tid; rloc = rloc < n_e ? rloc : n_e - 1;
        stok[tid] = tok_ids[off + rloc];
    }
    __syncthreads();

    int lane = tid & 63, w = tid >> 6;
    int wrow = (w >> 1)*64, wcol = (w & 1)*64;
    int q = lane >> 4, lm = lane & 15;

    // A staging (VGPR path): thread -> rows rA, rA+64; global granule gA
    int rA = tid >> 2, gA = tid & 3;
    const float* xr0 = x + (size_t)stok[rA]*DIM + gA*8;
    const float* xr1 = x + (size_t)stok[rA+64]*DIM + gA*8;
    f16* sA0 = &sA[rA*32       + ((gA ^ ((rA>>1)&3)) << 3)];
    f16* sA1 = &sA[(rA+64)*32  + ((gA ^ ((rA>>1)&3)) << 3)];   // same swizzle (+64 keeps (r>>1)&3)

    // B staging (DMA): wave w, chunks c=0,1 -> rows w*32+c*16+(lane>>2)
    int rB0 = w*32 + (lane >> 2);
    int rB1 = rB0 + 16;
    int jB0 = (lane & 3) ^ ((rB0 >> 1) & 3);
    int jB1 = (lane & 3) ^ ((rB1 >> 1) & 3);
    const f16* w1p = w1t + ((size_t)e*NH + nt*BN)*DIM;
    const f16* w3p = w3t + ((size_t)e*NH + nt*BN)*DIM;
    const f16* pB1_0 = w1p + (size_t)rB0*DIM + jB0*8;
    const f16* pB1_1 = w1p + (size_t)rB1*DIM + jB1*8;
    const f16* pB3_0 = w3p + (size_t)rB0*DIM + jB0*8;
    const f16* pB3_1 = w3p + (size_t)rB1*DIM + jB1*8;
    f16* lB1_0 = &sB1[rB0*32 + ((lane & 3) << 3)];
    f16* lB1_1 = &sB1[rB1*32 + ((lane & 3) << 3)];
    f16* lB3_0 = &sB3[rB0*32 + ((lane & 3) << 3)];
    f16* lB3_1 = &sB3[rB1*32 + ((lane & 3) << 3)];

    f32x4 acc1[4][4], acc3[4][4];
    #pragma unroll
    for (int a = 0; a < 4; a++)
        #pragma unroll
        for (int b = 0; b < 4; b++) {
            acc1[a][b] = (f32x4){0.f,0.f,0.f,0.f};
            acc3[a][b] = (f32x4){0.f,0.f,0.f,0.f};
        }

    for (int k0 = 0; k0 < DIM; k0 += BK) {
        __syncthreads();
        // DMA B first (latency overlapped by A's VGPR path)
        gl2lds16(pB1_0 + k0, lB1_0);
        gl2lds16(pB1_1 + k0, lB1_1);
        gl2lds16(pB3_0 + k0, lB3_0);
        gl2lds16(pB3_1 + k0, lB3_1);
        // A: fp32 load + cvt + swizzled ds_write_b128
        {
            float4 xa = *(const float4*)(xr0 + k0);
            float4 xb = *(const float4*)(xr0 + k0 + 4);
            *(f16x8*)sA0 = (f16x8){ (f16)xa.x,(f16)xa.y,(f16)xa.z,(f16)xa.w,
                                    (f16)xb.x,(f16)xb.y,(f16)xb.z,(f16)xb.w };
            float4 ya = *(const float4*)(xr1 + k0);
            float4 yb = *(const float4*)(xr1 + k0 + 4);
            *(f16x8*)sA1 = (f16x8){ (f16)ya.x,(f16)ya.y,(f16)ya.z,(f16)ya.w,
                                    (f16)yb.x,(f16)yb.y,(f16)yb.z,(f16)yb.w };
        }
        __syncthreads();   // drains vmcnt (DMA) + lgkm (ds_write)
        f16x8 aF[4], b1F[4], b3F[4];
        #pragma unroll
        for (int s = 0; s < 4; s++) {
            aF[s]  = FR(sA,  wrow + s*16 + lm, q);
            b1F[s] = FR(sB1, wcol + s*16 + lm, q);
            b3F[s] = FR(sB3, wcol + s*16 + lm, q);
        }
        #pragma unroll
        for (int sr = 0; sr < 4; sr++)
            #pragma unroll
            for (int sc = 0; sc < 4; sc++) {
                acc1[sr][sc] = __builtin_amdgcn_mfma_f32_16x16x32_f16(aF[sr], b1F[sc], acc1[sr][sc], 0, 0, 0);
                acc3[sr][sc] = __builtin_amdgcn_mfma_f32_16x16x32_f16(aF[sr], b3F[sc], acc3[sr][sc], 0, 0, 0);
            }
    }
    // epilogue: silu(h1)*h3 -> f16 gbuf.  C/D: col=lane&15, row=(lane>>4)*4+reg
    #pragma unroll
    for (int sr = 0; sr < 4; sr++) {
        #pragma unroll
        for (int reg = 0; reg < 4; reg++) {
            int row = mt*BM + wrow + sr*16 + q*4 + reg;
            if (row < n_e) {
                #pragma unroll
                for (int sc = 0; sc < 4; sc++) {
                    int col = nt*BN + wcol + sc*16 + lm;
                    float g1 = acc1[sr][sc][reg];
                    float g3 = acc3[sr][sc][reg];
                    float gv = g1 / (1.f + __expf(-g1)) * g3;
                    gbuf[(size_t)(off + row)*NH + col] = (f16)gv;
                }
            }
        }
    }
}

// GEMM2: ybuf[aid[row]] = gate * (G @ W2). Full DMA staging for A and B.
__global__ __launch_bounds__(256,4) void gemm2_kernel(
    const f16* __restrict__ gbuf, const f16* __restrict__ w2t,
    const int* __restrict__ offs, const int* __restrict__ aid,
    const float* __restrict__ row_gate, f16* __restrict__ ybuf)
{
    int bi = blockIdx.x;
    int e  = bi & 7;
    int r_ = bi >> 3;
    int nt = r_ & 7;          // DIM/BN = 8
    int mt = r_ >> 3;
    int off = offs[e];
    int n_e = offs[e+1] - off;
    if (mt*BM >= n_e) return;

    __shared__ f16 sA[BM*32];
    __shared__ f16 sB[BN*32];
    __shared__ int said[BM];
    __shared__ float sgate[BM];

    int tid = threadIdx.x;
    if (tid < BM) {
        int rloc = mt*BM + tid;
        if (rloc < n_e) { said[tid] = aid[off + rloc]; sgate[tid] = row_gate[off + rloc]; }
        else            { said[tid] = 0; sgate[tid] = 0.f; }
    }

    int lane = tid & 63, w = tid >> 6;
    int wrow = (w >> 1)*64, wcol = (w & 1)*64;
    int q = lane >> 4, lm = lane & 15;

    int rB0 = w*32 + (lane >> 2);
    int rB1 = rB0 + 16;
    int jB0 = (lane & 3) ^ ((rB0 >> 1) & 3);
    int jB1 = (lane & 3) ^ ((rB1 >> 1) & 3);
    int ra0 = mt*BM + rB0; ra0 = ra0 < n_e ? ra0 : n_e - 1;
    int ra1 = mt*BM + rB1; ra1 = ra1 < n_e ? ra1 : n_e - 1;
    const f16* pA0 = gbuf + (size_t)(off + ra0)*NH + jB0*8;
    const f16* pA1 = gbuf + (size_t)(off + ra1)*NH + jB1*8;
    const f16* w2p = w2t + ((size_t)e*DIM + nt*BN)*NH;
    const f16* pB0 = w2p + (size_t)rB0*NH + jB0*8;
    const f16* pB1 = w2p + (size_t)rB1*NH + jB1*8;
    f16* lA0 = &sA[rB0*32 + ((lane & 3) << 3)];
    f16* lA1 = &sA[rB1*32 + ((lane & 3) << 3)];
    f16* lB0 = &sB[rB0*32 + ((lane & 3) << 3)];
    f16* lB1 = &sB[rB1*32 + ((lane & 3) << 3)];

    f32x4 acc[4][4];
    #pragma unroll
    for (int a = 0; a < 4; a++)
        #pragma unroll
        for (int b = 0; b < 4; b++) acc[a][b] = (f32x4){0.f,0.f,0.f,0.f};

    __syncthreads();   // covers said/sgate writes; first DMA issues after

    for (int k0 = 0; k0 < NH; k0 += BK) {
        gl2lds16(pA0 + k0, lA0);
        gl2lds16(pA1 + k0, lA1);
        gl2lds16(pB0 + k0, lB0);
        gl2lds16(pB1 + k0, lB1);
        __syncthreads();   // drains vmcnt
        f16x8 aF[4], bF[4];
        #pragma unroll
        for (int s = 0; s < 4; s++) {
            aF[s] = FR(sA, wrow + s*16 + lm, q);
            bF[s] = FR(sB, wcol + s*16 + lm, q);
        }
        #pragma unroll
        for (int sr = 0; sr < 4; sr++)
            #pragma unroll
            for (int sc = 0; sc < 4; sc++)
                acc[sr][sc] = __builtin_amdgcn_mfma_f32_16x16x32_f16(aF[sr], bF[sc], acc[sr][sc], 0, 0, 0);
        __syncthreads();   // reads done before next iter's DMA overwrites
    }
    #pragma unroll
    for (int sr = 0; sr < 4; sr++) {
        #pragma unroll
        for (int reg = 0; reg < 4; reg++) {
            int lrow = wrow + sr*16 + q*4 + reg;
            if (mt*BM + lrow < n_e) {
                int id = said[lrow];
                float wgt = sgate[lrow];
                #pragma unroll
                for (int sc = 0; sc < 4; sc++) {
                    int col = nt*BN + wcol + sc*16 + lm;
                    ybuf[(size_t)id*DIM + col] = (f16)(wgt * acc[sr][sc][reg]);
                }
            }
        }
    }
}

// ---------------- combine: out[t] = ybuf[2t] + ybuf[2t+1] ----------------
__global__ __launch_bounds__(256) void combine_kernel(
    const f16* __restrict__ ybuf, float* __restrict__ out)
{
    int gid = blockIdx.x*256 + threadIdx.x;
    int t = gid >> 7;
    int c = (gid & 127) << 3;
    f16x8 y0 = *(const f16x8*)(ybuf + ((size_t)2*t)*DIM + c);
    f16x8 y1 = *(const f16x8*)(ybuf + ((size_t)2*t+1)*DIM + c);
    float* op = out + (size_t)t*DIM + c;
    float4 o0 = { (float)y0[0] + (float)y1[0], (float)y0[1] + (float)y1[1],
                  (float)y0[2] + (float)y1[2], (float)y0[3] + (float)y1[3] };
    float4 o1 = { (float)y0[4] + (float)y1[4], (float)y0[5] + (float)y1[5],
                  (float)y0[6] + (float)y1[6], (float)y0[7] + (float)y1[7] };
    *(float4*)op = o0;
    *(float4*)(op + 4) = o1;
}

extern "C" void kernel_launch(void* const* d_in, const int* in_sizes, int n_in,
                              void* d_out, int out_size, void* d_ws, size_t ws_size,
                              hipStream_t stream)
{
    const float* x  = (const float*)d_in[0];
    const float* wr = (const float*)d_in[1];
    const float* w1 = (const float*)d_in[2];
    const float* w2 = (const float*)d_in[3];
    const float* w3 = (const float*)d_in[4];
    float* out = (float*)d_out;

    char* ws = (char*)d_ws;
    f16* ybuf    = (f16*)ws;        ws += (size_t)NROWS*DIM*sizeof(f16);   // 32 MiB (writer: gemm2)
    f16* w1t     = (f16*)ws;        ws += (size_t)NE*NH*DIM*sizeof(f16);   // 8 MiB (writer: transpose)
    f16* w3t     = (f16*)ws;        ws += (size_t)NE*NH*DIM*sizeof(f16);   // 8 MiB (writer: transpose)
    f16* w2t     = (f16*)ws;        ws += (size_t)NE*DIM*NH*sizeof(f16);   // 8 MiB (writer: transpose)
    f16* gbuf    = (f16*)ws;        ws += (size_t)NROWS*NH*sizeof(f16);    // 16 MiB (writer: gemm1)
    float* plogits = (float*)ws;    ws += (size_t)2*NT*NE*4;               // 512 KiB (writer: router)
    int* tok_ids = (int*)ws;        ws += (size_t)NROWS*4;                 // (writer: finalize)
    int* aid     = (int*)ws;        ws += (size_t)NROWS*4;
    float* row_gate = (float*)ws;   ws += (size_t)NROWS*4;
    int* offs    = (int*)ws;        ws += 64;
    if (ws_size < (size_t)(ws - (char*)d_ws)) return;  // ~72.7 MB needed

    router_logits_kernel<<<dim3(NT/16, 2), 256, 0, stream>>>(x, wr, plogits);
    finalize_kernel<<<1, 1024, 0, stream>>>(plogits, tok_ids, aid, row_gate, offs);
    transpose_fused_kernel<<<dim3(512, 24), dim3(32, 8), 0, stream>>>(w1, w3, w2, w1t, w3t, w2t);
    gemm1_kernel<<<4096, 256, 0, stream>>>(x, tok_ids, w1t, w3t, gbuf, offs);
    gemm2_kernel<<<8192, 256, 0, stream>>>(gbuf, w2t, offs, aid, row_gate, ybuf);
    combine_kernel<<<(NT*(DIM/8))/256, 256, 0, stream>>>(ybuf, out);
}